// Round 8
// baseline (175.194 us; speedup 1.0000x reference)
//
#include <hip/hip_runtime.h>
#include <cstdint>
#include <cstddef>

#define S_DIM 1024
#define NPTS (S_DIM * S_DIM)
#define NLEV 16
#define TBL (1u << 19)
#define TMASK (TBL - 1u)
#define PRIME_Y 2654435761u

typedef float v4f __attribute__((ext_vector_type(4)));
typedef short v8s __attribute__((ext_vector_type(8)));

// all 16 level resolutions; levels 0-9 are DENSE ((res+1)^2 <= 2^19), 10-15 hashed
static constexpr int RES_ALL[NLEV] = {16, 24, 36, 54, 81, 121, 182, 273,
                                      410, 615, 922, 1383, 2075, 3113, 4670, 7006};
// dense-level corner staging: worst-case distinct corner-x count per level
// = ceil(res/4) + 2 (block spans 256 points = res/4 cells in x), and prefix
// offsets into the stage buffer (float4 units). Sum = 477 (7632 B).
static constexpr int DCNT[10] = {6, 8, 11, 16, 23, 33, 48, 71, 105, 156};
static constexpr int DOFF[10] = {0, 6, 14, 25, 41, 64, 97, 145, 216, 321};
#define DTOT 477

// ---- split-bf16 helpers: x = hi + lo, both truncated bf16 ----
__device__ __forceinline__ void split2(float a, float b, uint32_t& hi, uint32_t& lo) {
    uint32_t ua = __float_as_uint(a), ub = __float_as_uint(b);
    uint32_t ha = ua & 0xFFFF0000u, hb = ub & 0xFFFF0000u;
    float la = a - __uint_as_float(ha);
    float lb = b - __uint_as_float(hb);
    hi = (ha >> 16) | hb;
    lo = (__float_as_uint(la) >> 16) | (__float_as_uint(lb) & 0xFFFF0000u);
}

// ============================================================================
// Pre-pass (now 3 blocks): bf16 hi/lo A-fragments of W0^T and W1^T into d_ws.
// ws as uint4: [0,256) W0hi | [256,512) W0lo | [512,1024) W1hi | [1024,1536) W1lo
// ============================================================================
__global__ __launch_bounds__(256) void prep_weights(const float* __restrict__ W0,
                                                    const float* __restrict__ W1,
                                                    uint4* __restrict__ ws) {
    const int tid = threadIdx.x;          // 0..255
    const int b = blockIdx.x;             // 0..2

    if (b == 0) {   // W0^T: 4 n-tiles, 1 k-step. unit = tid.
        const int lane = tid & 63;
        const int m = lane & 15, q = lane >> 4;
        const int tile = tid >> 6;
        const int n = tile * 16 + m;
        uint32_t hi[4], lo[4];
        #pragma unroll
        for (int d = 0; d < 4; ++d) {
            const int k0 = q * 8 + 2 * d;
            split2(W0[k0 * 64 + n], W0[(k0 + 1) * 64 + n], hi[d], lo[d]);
        }
        ws[tid]       = make_uint4(hi[0], hi[1], hi[2], hi[3]);
        ws[256 + tid] = make_uint4(lo[0], lo[1], lo[2], lo[3]);
    } else {        // W1^T: 8 frags (nt*2+ks) x 64 lanes; unit in [0,512)
        const int unit = tid + (b - 1) * 256;
        const int l2 = unit & 63, frag = unit >> 6;
        const int nt = frag >> 1, ks = frag & 1;
        const int mm = l2 & 15, qq = l2 >> 4;
        const int n = nt * 16 + mm;
        uint32_t hi[4], lo[4];
        #pragma unroll
        for (int d = 0; d < 4; ++d) {
            const int k0 = ks * 32 + qq * 8 + 2 * d;
            split2(W1[k0 * 64 + n], W1[(k0 + 1) * 64 + n], hi[d], lo[d]);
        }
        ws[512 + unit]  = make_uint4(hi[0], hi[1], hi[2], hi[3]);
        ws[1024 + unit] = make_uint4(lo[0], lo[1], lo[2], lo[3]);
    }
}

// ---- per-level hash-grid feature (hash levels only now; verified all rounds)
static __device__ __forceinline__ float2 level_feat(float x, float y, int res,
                                                    const float* __restrict__ tb) {
    const float fr = (float)res;
    const float px = x * fr, py = y * fr;
    const float fx = floorf(px), fy = floorf(py);
    const float wx = px - fx, wy = py - fy;
    const int x0 = (int)fx, y0 = (int)fy;

    int i00, i01, i10, i11;
    const bool dense = ((long long)(res + 1) * (long long)(res + 1) <= (long long)TBL);
    if (dense) {
        const int st = res + 1;
        i00 = x0 + y0 * st;
        i01 = i00 + st;
        i10 = i00 + 1;
        i11 = i01 + 1;
    } else {
        const unsigned a = (unsigned)x0, b = (unsigned)y0;
        const unsigned hb0 = b * PRIME_Y;
        const unsigned hb1 = (b + 1u) * PRIME_Y;
        i00 = (int)((a ^ hb0) & TMASK);
        i01 = (int)((a ^ hb1) & TMASK);
        i10 = (int)(((a + 1u) ^ hb0) & TMASK);
        i11 = (int)(((a + 1u) ^ hb1) & TMASK);
    }

    const float2 f00 = *(const float2*)(tb + 2 * (size_t)i00);
    const float2 f01 = *(const float2*)(tb + 2 * (size_t)i01);
    const float2 f10 = *(const float2*)(tb + 2 * (size_t)i10);
    const float2 f11 = *(const float2*)(tb + 2 * (size_t)i11);

    const float omx = 1.f - wx, omy = 1.f - wy;
    const float w00 = omx * omy, w01 = omx * wy, w10 = wx * omy, w11 = wx * wy;

    float2 e;
    e.x = f00.x * w00 + f01.x * w01 + f10.x * w10 + f11.x * w11;
    e.y = f00.y * w00 + f01.y * w01 + f10.y * w10 + f11.y * w11;
    return e;
}

// ============================================================================
// Main kernel.  r7 structure (3 blocks/CU, no spill) + DENSE-LEVEL CORNER
// STAGING: each block is 256 consecutive points of ONE grid row (y uniform,
// x spans res/4 cells), so levels 0-9's entire corner set is 477 float4s.
// Stage them cooperatively (reusing w1LDS space), then dense levels read
// 2 aligned ds_read_b128 instead of issuing 4 global gathers + full addr math.
// W1-frag staging moves to AFTER the encode (same LDS bytes, L2-hot loads).
// Hash levels 10-15 keep the verified per-point path.  Phase 2 unchanged.
// X0/y0 derive from xy[blockBase] (read by both stager and encode lanes ->
// bit-consistent).  Staged x clamped to res; xi in [0, DCNT-2] by f32-mul
// monotonicity.  LDS: enc 36864 + w1/stage 16384 = 53248 -> 3 blocks/CU.
// Spill tripwire: WRITE_SIZE > 30 MB means the reg budget failed.
// ============================================================================
__global__ __launch_bounds__(256, 3) void ngp_mfma(
    const float* __restrict__ xy,
    const float* __restrict__ tables,
    const float* __restrict__ W2,
    const uint4* __restrict__ ws,
    float* __restrict__ out)
{
    // enc rows: 256 points x (16 hi | 16 lo dwords) = 128B, padded to 144B.
    // Rows double as the per-tile h0 bounce space (r7-verified).
    __shared__ alignas(16) uint32_t encLDS[256 * 36];        // 36864 B
    // Phase 1: dense corner stage (float4[477]).  Phase 2: W1^T fragments.
    __shared__ alignas(16) uint4 w1LDS[1024];                // 16384 B
    // total: 53248 B = 26 x 2048 exactly -> 3 blocks/CU

    const int tid = threadIdx.x;
    const int lane = tid & 63;
    const int wave = tid >> 6;
    const int m = lane & 15, q = lane >> 4;
    const int blockBase = blockIdx.x * 256;

    const float2 p00 = ((const float2*)xy)[blockBase];   // block's first point

    // ---------------- Phase 0: stage dense-level corner rows ----------------
    {
        float4* stage = (float4*)w1LDS;
        for (int u = tid; u < DTOT; u += 256) {
            int l = 0;
            #pragma unroll
            for (int k = 1; k < 10; ++k) l += (u >= DOFF[k]);
            const int r  = RES_ALL[l];
            const float fr = (float)r;
            const int X0 = (int)floorf(p00.x * fr);
            const int x  = min(X0 + (u - DOFF[l]), r);
            const int y0 = (int)floorf(p00.y * fr);
            const int st = r + 1;
            const float* tb = tables + (size_t)l * (size_t)(TBL * 2u);
            const float2 f0 = *(const float2*)(tb + 2 * (size_t)(x + y0 * st));
            const float2 f1 = *(const float2*)(tb + 2 * (size_t)(x + y0 * st + st));
            stage[u] = make_float4(f0.x, f0.y, f1.x, f1.y);
        }
    }
    __syncthreads();   // stage visible to all waves

    // ---------------- Phase 1: encode own point ----------------
    {
        const int pid = blockBase + tid;
        const float2 p = ((const float2*)xy)[pid];
        const float4* stage = (const float4*)w1LDS;
        uint32_t* row = encLDS + tid * 36;

        // groups 0,1: dense levels 0-7 from stage
        #pragma unroll
        for (int g = 0; g < 2; ++g) {
            uint32_t hi[4], lo[4];
            #pragma unroll
            for (int i = 0; i < 4; ++i) {
                const int l = g * 4 + i;
                const float fr = (float)RES_ALL[l];
                const float px = p.x * fr, py = p.y * fr;
                const float fx = floorf(px), fy = floorf(py);
                const float wx = px - fx, wy = py - fy;
                const int xi = (int)fx - (int)floorf(p00.x * fr);
                const float4 c0 = stage[DOFF[l] + xi];       // f00 | f01
                const float4 c1 = stage[DOFF[l] + xi + 1];   // f10 | f11
                const float omx = 1.f - wx, omy = 1.f - wy;
                const float w00 = omx * omy, w01 = omx * wy;
                const float w10 = wx * omy,  w11 = wx * wy;
                float2 e;
                e.x = c0.x * w00 + c0.z * w01 + c1.x * w10 + c1.z * w11;
                e.y = c0.y * w00 + c0.w * w01 + c1.y * w10 + c1.w * w11;
                split2(e.x, e.y, hi[i], lo[i]);
            }
            *((uint4*)(row + 4 * g))      = make_uint4(hi[0], hi[1], hi[2], hi[3]);
            *((uint4*)(row + 16 + 4 * g)) = make_uint4(lo[0], lo[1], lo[2], lo[3]);
        }
        // group 2: levels 8,9 dense + 10,11 hashed
        {
            uint32_t hi[4], lo[4];
            #pragma unroll
            for (int i = 0; i < 2; ++i) {
                const int l = 8 + i;
                const float fr = (float)RES_ALL[l];
                const float px = p.x * fr, py = p.y * fr;
                const float fx = floorf(px), fy = floorf(py);
                const float wx = px - fx, wy = py - fy;
                const int xi = (int)fx - (int)floorf(p00.x * fr);
                const float4 c0 = stage[DOFF[l] + xi];
                const float4 c1 = stage[DOFF[l] + xi + 1];
                const float omx = 1.f - wx, omy = 1.f - wy;
                const float w00 = omx * omy, w01 = omx * wy;
                const float w10 = wx * omy,  w11 = wx * wy;
                float2 e;
                e.x = c0.x * w00 + c0.z * w01 + c1.x * w10 + c1.z * w11;
                e.y = c0.y * w00 + c0.w * w01 + c1.y * w10 + c1.w * w11;
                split2(e.x, e.y, hi[i], lo[i]);
            }
            #pragma unroll
            for (int i = 2; i < 4; ++i) {
                const int l = 8 + i;
                const float2 e = level_feat(p.x, p.y, RES_ALL[l],
                                            tables + (size_t)l * (size_t)(TBL * 2u));
                split2(e.x, e.y, hi[i], lo[i]);
            }
            *((uint4*)(row + 8))      = make_uint4(hi[0], hi[1], hi[2], hi[3]);
            *((uint4*)(row + 16 + 8)) = make_uint4(lo[0], lo[1], lo[2], lo[3]);
        }
        // group 3: levels 12-15 hashed
        {
            uint32_t hi[4], lo[4];
            #pragma unroll
            for (int i = 0; i < 4; ++i) {
                const int l = 12 + i;
                const float2 e = level_feat(p.x, p.y, RES_ALL[l],
                                            tables + (size_t)l * (size_t)(TBL * 2u));
                split2(e.x, e.y, hi[i], lo[i]);
            }
            *((uint4*)(row + 12))      = make_uint4(hi[0], hi[1], hi[2], hi[3]);
            *((uint4*)(row + 16 + 12)) = make_uint4(lo[0], lo[1], lo[2], lo[3]);
        }
    }

    __syncthreads();   // all waves done reading stage -> safe to overwrite

    // ---------------- stage W1 frags global->LDS (overwrites stage) --------
    #pragma unroll
    for (int i = 0; i < 4; ++i) w1LDS[tid + 256 * i] = ws[512 + tid + 256 * i];

    __syncthreads();   // w1LDS visible

    // keep encode and phase-2 live ranges disjoint: no motion across here
    __builtin_amdgcn_sched_barrier(0);

    // ---------------- W0 fragments: registers, reused by all 4 tiles -------
    v8s w0h[4], w0l[4];
    #pragma unroll
    for (int t = 0; t < 4; ++t) {
        w0h[t] = __builtin_bit_cast(v8s, ws[t * 64 + lane]);
        w0l[t] = __builtin_bit_cast(v8s, ws[256 + t * 64 + lane]);
    }

    // ---------------- Phase 2: 4 M-tiles of 16 points (r7-verified) --------
    #pragma unroll 1
    for (int t = 0; t < 4; ++t) {
        // launder a zero through opaque asm so LICM cannot hoist the
        // per-tile w1LDS reads / W2 global reads out of this loop.
        int tOff = 0;
        asm volatile("" : "+v"(tOff));

        // this tile's enc row for lane's m — also the h0 bounce row.
        uint32_t* hrow = encLDS + (wave * 64 + t * 16 + m) * 36;

        // B-frag of enc: point p = wave*64 + t*16 + m
        const v8s eH = __builtin_bit_cast(v8s, *((const uint4*)(hrow + q * 4)));
        const v8s eL = __builtin_bit_cast(v8s, *((const uint4*)(hrow + 16 + q * 4)));

        // ---- L0: D0[n][p] = W0^T x enc^T, 3-term split ----
        v4f acc0[4];
        #pragma unroll
        for (int nt = 0; nt < 4; ++nt) {
            v4f c = {0.f, 0.f, 0.f, 0.f};
            c = __builtin_amdgcn_mfma_f32_16x16x32_bf16(w0l[nt], eH, c, 0, 0, 0);
            c = __builtin_amdgcn_mfma_f32_16x16x32_bf16(w0h[nt], eL, c, 0, 0, 0);
            c = __builtin_amdgcn_mfma_f32_16x16x32_bf16(w0h[nt], eH, c, 0, 0, 0);
            acc0[nt] = c;
        }

        v4f acc1[4];
        #pragma unroll
        for (int nt = 0; nt < 4; ++nt) acc1[nt] = (v4f){0.f, 0.f, 0.f, 0.f};

        // ---- L1 in two ks-halves, bouncing through this tile's enc rows ----
        #pragma unroll
        for (int ks = 0; ks < 2; ++ks) {
            #pragma unroll
            for (int nh = 0; nh < 2; ++nh) {
                const int nt = ks * 2 + nh;
                const float r0 = fmaxf(acc0[nt][0], 0.f), r1 = fmaxf(acc0[nt][1], 0.f);
                const float r2 = fmaxf(acc0[nt][2], 0.f), r3 = fmaxf(acc0[nt][3], 0.f);
                uint32_t h0w, l0w, h1w, l1w;
                split2(r0, r1, h0w, l0w);
                split2(r2, r3, h1w, l1w);
                *((uint2*)(hrow + nh * 8 + q * 2))      = make_uint2(h0w, h1w);
                *((uint2*)(hrow + 16 + nh * 8 + q * 2)) = make_uint2(l0w, l1w);
            }
            const v8s bH = __builtin_bit_cast(v8s, *((const uint4*)(hrow + q * 4)));
            const v8s bL = __builtin_bit_cast(v8s, *((const uint4*)(hrow + 16 + q * 4)));

            #pragma unroll
            for (int nt = 0; nt < 4; ++nt) {
                const v8s a_h = __builtin_bit_cast(v8s, w1LDS[tOff + (nt * 2 + ks) * 64 + lane]);
                const v8s a_l = __builtin_bit_cast(v8s, w1LDS[tOff + 512 + (nt * 2 + ks) * 64 + lane]);
                v4f c = acc1[nt];
                c = __builtin_amdgcn_mfma_f32_16x16x32_bf16(a_l, bH, c, 0, 0, 0);
                c = __builtin_amdgcn_mfma_f32_16x16x32_bf16(a_h, bL, c, 0, 0, 0);
                c = __builtin_amdgcn_mfma_f32_16x16x32_bf16(a_h, bH, c, 0, 0, 0);
                acc1[nt] = c;
            }
        }

        // ---- L2 (64->3) in VALU: W2 direct from global (768 B, L1-hot) ----
        float o0 = 0.f, o1 = 0.f, o2 = 0.f;
        #pragma unroll
        for (int nt = 0; nt < 4; ++nt) {
            const int n0 = nt * 16 + q * 4;
            const float4 g0 = *((const float4*)(W2 + n0 * 3 + tOff));
            const float4 g1 = *((const float4*)(W2 + n0 * 3 + tOff + 4));
            const float4 g2 = *((const float4*)(W2 + n0 * 3 + tOff + 8));
            const float h0r = fmaxf(acc1[nt][0], 0.f), h1r = fmaxf(acc1[nt][1], 0.f);
            const float h2r = fmaxf(acc1[nt][2], 0.f), h3r = fmaxf(acc1[nt][3], 0.f);
            o0 = fmaf(h0r, g0.x, fmaf(h1r, g0.w, fmaf(h2r, g1.z, fmaf(h3r, g2.y, o0))));
            o1 = fmaf(h0r, g0.y, fmaf(h1r, g1.x, fmaf(h2r, g1.w, fmaf(h3r, g2.z, o1))));
            o2 = fmaf(h0r, g0.z, fmaf(h1r, g1.y, fmaf(h2r, g2.x, fmaf(h3r, g2.w, o2))));
        }
        o0 += __shfl_xor(o0, 16); o0 += __shfl_xor(o0, 32);
        o1 += __shfl_xor(o1, 16); o1 += __shfl_xor(o1, 32);
        o2 += __shfl_xor(o2, 16); o2 += __shfl_xor(o2, 32);

        if (lane < 16) {
            const int p = blockBase + wave * 64 + t * 16 + lane;
            out[p] = o0;
            out[NPTS + p] = o1;
            out[2 * NPTS + p] = o2;
        }
    }
}

extern "C" void kernel_launch(void* const* d_in, const int* in_sizes, int n_in,
                              void* d_out, int out_size, void* d_ws, size_t ws_size,
                              hipStream_t stream) {
    const float* xy     = (const float*)d_in[0];
    const float* tables = (const float*)d_in[1];
    const float* W0     = (const float*)d_in[2];
    const float* W1     = (const float*)d_in[3];
    const float* W2     = (const float*)d_in[4];
    float* out = (float*)d_out;
    uint4* ws  = (uint4*)d_ws;   // 1536 x 16B = 24 KB

    hipLaunchKernelGGL(prep_weights, dim3(3), dim3(256), 0, stream, W0, W1, ws);
    hipLaunchKernelGGL(ngp_mfma, dim3(NPTS / 256), dim3(256), 0, stream,
                       xy, tables, W2, ws, out);
}

// Round 9
// 170.599 us; speedup vs baseline: 1.0269x; 1.0269x over previous
//
#include <hip/hip_runtime.h>
#include <cstdint>
#include <cstddef>

#define S_DIM 1024
#define NPTS (S_DIM * S_DIM)
#define NLEV 16
#define TBL (1u << 19)
#define TMASK (TBL - 1u)
#define PRIME_Y 2654435761u

typedef float v4f __attribute__((ext_vector_type(4)));
typedef short v8s __attribute__((ext_vector_type(8)));
typedef float f2 __attribute__((ext_vector_type(2)));
typedef float f4 __attribute__((ext_vector_type(4)));

// all 16 level resolutions; levels 0-9 are DENSE ((res+1)^2 <= 2^19), 10-15 hashed
static constexpr int RES_ALL[NLEV] = {16, 24, 36, 54, 81, 121, 182, 273,
                                      410, 615, 922, 1383, 2075, 3113, 4670, 7006};
// dense-level corner staging (r8-verified): distinct corner-x count per level
// and prefix offsets (float4 units). Sum = 477 (7632 B).
static constexpr int DCNT[10] = {6, 8, 11, 16, 23, 33, 48, 71, 105, 156};
static constexpr int DOFF[10] = {0, 6, 14, 25, 41, 64, 97, 145, 216, 321};
#define DTOT 477

// ---- split-bf16: x = hi + lo, both truncated bf16.  v_perm_b32 packs each
// output word in ONE op (bytes [ua.b2,ua.b3,ub.b2,ub.b3] = (ha>>16)|(hb&hi16))
// -- bit-identical to the shift/or version, 6 ops instead of ~10. ----
__device__ __forceinline__ void split2(float a, float b, uint32_t& hi, uint32_t& lo) {
    uint32_t ua = __float_as_uint(a), ub = __float_as_uint(b);
    float la = a - __uint_as_float(ua & 0xFFFF0000u);
    float lb = b - __uint_as_float(ub & 0xFFFF0000u);
    hi = __builtin_amdgcn_perm(ub, ua, 0x07060302u);
    lo = __builtin_amdgcn_perm(__float_as_uint(lb), __float_as_uint(la), 0x07060302u);
}

// ============================================================================
// Pre-pass (3 blocks): bf16 hi/lo A-fragments of W0^T and W1^T into d_ws.
// ws as uint4: [0,256) W0hi | [256,512) W0lo | [512,1024) W1hi | [1024,1536) W1lo
// ============================================================================
__global__ __launch_bounds__(256) void prep_weights(const float* __restrict__ W0,
                                                    const float* __restrict__ W1,
                                                    uint4* __restrict__ ws) {
    const int tid = threadIdx.x;          // 0..255
    const int b = blockIdx.x;             // 0..2

    if (b == 0) {   // W0^T: 4 n-tiles, 1 k-step. unit = tid.
        const int lane = tid & 63;
        const int m = lane & 15, q = lane >> 4;
        const int tile = tid >> 6;
        const int n = tile * 16 + m;
        uint32_t hi[4], lo[4];
        #pragma unroll
        for (int d = 0; d < 4; ++d) {
            const int k0 = q * 8 + 2 * d;
            split2(W0[k0 * 64 + n], W0[(k0 + 1) * 64 + n], hi[d], lo[d]);
        }
        ws[tid]       = make_uint4(hi[0], hi[1], hi[2], hi[3]);
        ws[256 + tid] = make_uint4(lo[0], lo[1], lo[2], lo[3]);
    } else {        // W1^T: 8 frags (nt*2+ks) x 64 lanes; unit in [0,512)
        const int unit = tid + (b - 1) * 256;
        const int l2 = unit & 63, frag = unit >> 6;
        const int nt = frag >> 1, ks = frag & 1;
        const int mm = l2 & 15, qq = l2 >> 4;
        const int n = nt * 16 + mm;
        uint32_t hi[4], lo[4];
        #pragma unroll
        for (int d = 0; d < 4; ++d) {
            const int k0 = ks * 32 + qq * 8 + 2 * d;
            split2(W1[k0 * 64 + n], W1[(k0 + 1) * 64 + n], hi[d], lo[d]);
        }
        ws[512 + unit]  = make_uint4(hi[0], hi[1], hi[2], hi[3]);
        ws[1024 + unit] = make_uint4(lo[0], lo[1], lo[2], lo[3]);
    }
}

// ---- hash-level gather/interp, two-stage so gathers can issue early --------
struct HashLvl {
    f2 f00, f01, f10, f11;
    float wx, wy;
};
static __device__ __forceinline__ HashLvl hash_load(float x, float y, int res,
                                                    const float* __restrict__ tb) {
    const float fr = (float)res;
    const float px = x * fr, py = y * fr;
    const float fx = floorf(px), fy = floorf(py);
    HashLvl h;
    h.wx = px - fx;
    h.wy = py - fy;
    const unsigned a = (unsigned)(int)fx, b = (unsigned)(int)fy;
    const unsigned hb0 = b * PRIME_Y;
    const unsigned hb1 = hb0 + PRIME_Y;          // == (b+1)*PRIME mod 2^32
    const int i00 = (int)((a ^ hb0) & TMASK);
    const int i01 = (int)((a ^ hb1) & TMASK);
    const int i10 = (int)(((a + 1u) ^ hb0) & TMASK);
    const int i11 = (int)(((a + 1u) ^ hb1) & TMASK);
    h.f00 = *(const f2*)(tb + 2 * (size_t)i00);
    h.f01 = *(const f2*)(tb + 2 * (size_t)i01);
    h.f10 = *(const f2*)(tb + 2 * (size_t)i10);
    h.f11 = *(const f2*)(tb + 2 * (size_t)i11);
    return h;
}
static __device__ __forceinline__ f2 hash_interp(const HashLvl& h) {
    const float omx = 1.f - h.wx, omy = 1.f - h.wy;
    const float w00 = omx * omy, w01 = omx * h.wy;
    const float w10 = h.wx * omy, w11 = h.wx * h.wy;
    // packed f32: same mul->fma->fma->fma contraction per component
    return h.f00 * w00 + h.f01 * w01 + h.f10 * w10 + h.f11 * w11;
}

// ---- dense-level interp from the LDS corner stage (packed f32) -------------
static __device__ __forceinline__ f2 dense_interp(const f4* __restrict__ stage,
                                                  int l, f2 p, float p00x) {
    const float fr = (float)RES_ALL[l];
    const float px = p.x * fr, py = p.y * fr;
    const float fx = floorf(px), fy = floorf(py);
    const float wx = px - fx, wy = py - fy;
    const int xi = (int)fx - (int)floorf(p00x * fr);
    const f4 c0 = stage[DOFF[l] + xi];       // f00 | f01
    const f4 c1 = stage[DOFF[l] + xi + 1];   // f10 | f11
    const float omx = 1.f - wx, omy = 1.f - wy;
    const float w00 = omx * omy, w01 = omx * wy;
    const float w10 = wx * omy,  w11 = wx * wy;
    return c0.xy * w00 + c0.zw * w01 + c1.xy * w10 + c1.zw * w11;
}

// ============================================================================
// Main kernel.  r8 structure (3 blocks/CU, no spill, dense corner staging)
// + round-9 VALU/latency work:
//   - perm-based split2 (~-190 VALU/thread), packed-f32 interp (~-100)
//   - ALL 24 hash gathers (levels 10-15) issue BEFORE the dense-level work,
//     consumed after -> dense VALU (~250 ops) runs under gather latency.
//     In-flight state ~60 VGPR; budget audit ~100 total << 168.
// Phase 2 (MFMA + bounce-through-enc-rows), LDS map (enc 36864 + w1 16384 =
// 53248 = 3 blocks/CU), pre-pass: unchanged (r8-verified).
// Spill tripwire: WRITE_SIZE > 30 MB means the reg budget failed.
// ============================================================================
__global__ __launch_bounds__(256, 3) void ngp_mfma(
    const float* __restrict__ xy,
    const float* __restrict__ tables,
    const float* __restrict__ W2,
    const uint4* __restrict__ ws,
    float* __restrict__ out)
{
    // enc rows: 256 points x (16 hi | 16 lo dwords) = 128B, padded to 144B.
    // Rows double as the per-tile h0 bounce space (r7/r8-verified).
    __shared__ alignas(16) uint32_t encLDS[256 * 36];        // 36864 B
    // Phase 1: dense corner stage (f4[477]).  Phase 2: W1^T fragments.
    __shared__ alignas(16) uint4 w1LDS[1024];                // 16384 B
    // total: 53248 B = 26 x 2048 exactly -> 3 blocks/CU

    const int tid = threadIdx.x;
    const int lane = tid & 63;
    const int wave = tid >> 6;
    const int m = lane & 15, q = lane >> 4;
    const int blockBase = blockIdx.x * 256;

    const float2 p00 = ((const float2*)xy)[blockBase];   // block's first point

    // ---------------- Phase 0: stage dense-level corner rows ----------------
    {
        f4* stage = (f4*)w1LDS;
        for (int u = tid; u < DTOT; u += 256) {
            int l = 0;
            #pragma unroll
            for (int k = 1; k < 10; ++k) l += (u >= DOFF[k]);
            const int r  = RES_ALL[l];
            const float fr = (float)r;
            const int X0 = (int)floorf(p00.x * fr);
            const int x  = min(X0 + (u - DOFF[l]), r);
            const int y0 = (int)floorf(p00.y * fr);
            const int st = r + 1;
            const float* tb = tables + (size_t)l * (size_t)(TBL * 2u);
            const float2 f0 = *(const float2*)(tb + 2 * (size_t)(x + y0 * st));
            const float2 f1 = *(const float2*)(tb + 2 * (size_t)(x + y0 * st + st));
            stage[u] = (f4){f0.x, f0.y, f1.x, f1.y};
        }
    }
    __syncthreads();   // stage visible to all waves

    // ---------------- Phase 1: encode own point ----------------
    {
        const int pid = blockBase + tid;
        const f2 p = *((const f2*)(xy + 2 * (size_t)pid));
        const f4* stage = (const f4*)w1LDS;
        uint32_t* row = encLDS + tid * 36;

        // -- A: issue ALL hash gathers (levels 10-15) early; 24 independent
        //       8B loads go in flight before any dense work consumes VALU.
        HashLvl hl[6];
        #pragma unroll
        for (int i = 0; i < 6; ++i)
            hl[i] = hash_load(p.x, p.y, RES_ALL[10 + i],
                              tables + (size_t)(10 + i) * (size_t)(TBL * 2u));

        // -- B: dense groups 0,1 (levels 0-7) from LDS stage, under gather
        //       latency.
        #pragma unroll
        for (int g = 0; g < 2; ++g) {
            uint32_t hi[4], lo[4];
            #pragma unroll
            for (int i = 0; i < 4; ++i) {
                const f2 e = dense_interp(stage, g * 4 + i, p, p00.x);
                split2(e.x, e.y, hi[i], lo[i]);
            }
            *((uint4*)(row + 4 * g))      = make_uint4(hi[0], hi[1], hi[2], hi[3]);
            *((uint4*)(row + 16 + 4 * g)) = make_uint4(lo[0], lo[1], lo[2], lo[3]);
        }

        // -- C: group 2 = levels 8,9 dense + 10,11 hashed (consume hl[0..1])
        {
            uint32_t hi[4], lo[4];
            #pragma unroll
            for (int i = 0; i < 2; ++i) {
                const f2 e = dense_interp(stage, 8 + i, p, p00.x);
                split2(e.x, e.y, hi[i], lo[i]);
            }
            #pragma unroll
            for (int i = 0; i < 2; ++i) {
                const f2 e = hash_interp(hl[i]);
                split2(e.x, e.y, hi[2 + i], lo[2 + i]);
            }
            *((uint4*)(row + 8))      = make_uint4(hi[0], hi[1], hi[2], hi[3]);
            *((uint4*)(row + 16 + 8)) = make_uint4(lo[0], lo[1], lo[2], lo[3]);
        }
        // -- D: group 3 = levels 12-15 hashed (consume hl[2..5])
        {
            uint32_t hi[4], lo[4];
            #pragma unroll
            for (int i = 0; i < 4; ++i) {
                const f2 e = hash_interp(hl[2 + i]);
                split2(e.x, e.y, hi[i], lo[i]);
            }
            *((uint4*)(row + 12))      = make_uint4(hi[0], hi[1], hi[2], hi[3]);
            *((uint4*)(row + 16 + 12)) = make_uint4(lo[0], lo[1], lo[2], lo[3]);
        }
    }

    __syncthreads();   // all waves done reading stage -> safe to overwrite

    // ---------------- stage W1 frags global->LDS (overwrites stage) --------
    #pragma unroll
    for (int i = 0; i < 4; ++i) w1LDS[tid + 256 * i] = ws[512 + tid + 256 * i];

    __syncthreads();   // w1LDS visible

    // keep encode and phase-2 live ranges disjoint: no motion across here
    __builtin_amdgcn_sched_barrier(0);

    // ---------------- W0 fragments: registers, reused by all 4 tiles -------
    v8s w0h[4], w0l[4];
    #pragma unroll
    for (int t = 0; t < 4; ++t) {
        w0h[t] = __builtin_bit_cast(v8s, ws[t * 64 + lane]);
        w0l[t] = __builtin_bit_cast(v8s, ws[256 + t * 64 + lane]);
    }

    // ---------------- Phase 2: 4 M-tiles of 16 points (r7/r8-verified) -----
    #pragma unroll 1
    for (int t = 0; t < 4; ++t) {
        // launder a zero through opaque asm so LICM cannot hoist the
        // per-tile w1LDS reads / W2 global reads out of this loop.
        int tOff = 0;
        asm volatile("" : "+v"(tOff));

        // this tile's enc row for lane's m — also the h0 bounce row.
        uint32_t* hrow = encLDS + (wave * 64 + t * 16 + m) * 36;

        // B-frag of enc: point p = wave*64 + t*16 + m
        const v8s eH = __builtin_bit_cast(v8s, *((const uint4*)(hrow + q * 4)));
        const v8s eL = __builtin_bit_cast(v8s, *((const uint4*)(hrow + 16 + q * 4)));

        // ---- L0: D0[n][p] = W0^T x enc^T, 3-term split ----
        v4f acc0[4];
        #pragma unroll
        for (int nt = 0; nt < 4; ++nt) {
            v4f c = {0.f, 0.f, 0.f, 0.f};
            c = __builtin_amdgcn_mfma_f32_16x16x32_bf16(w0l[nt], eH, c, 0, 0, 0);
            c = __builtin_amdgcn_mfma_f32_16x16x32_bf16(w0h[nt], eL, c, 0, 0, 0);
            c = __builtin_amdgcn_mfma_f32_16x16x32_bf16(w0h[nt], eH, c, 0, 0, 0);
            acc0[nt] = c;
        }

        v4f acc1[4];
        #pragma unroll
        for (int nt = 0; nt < 4; ++nt) acc1[nt] = (v4f){0.f, 0.f, 0.f, 0.f};

        // ---- L1 in two ks-halves, bouncing through this tile's enc rows ----
        #pragma unroll
        for (int ks = 0; ks < 2; ++ks) {
            #pragma unroll
            for (int nh = 0; nh < 2; ++nh) {
                const int nt = ks * 2 + nh;
                const float r0 = fmaxf(acc0[nt][0], 0.f), r1 = fmaxf(acc0[nt][1], 0.f);
                const float r2 = fmaxf(acc0[nt][2], 0.f), r3 = fmaxf(acc0[nt][3], 0.f);
                uint32_t h0w, l0w, h1w, l1w;
                split2(r0, r1, h0w, l0w);
                split2(r2, r3, h1w, l1w);
                *((uint2*)(hrow + nh * 8 + q * 2))      = make_uint2(h0w, h1w);
                *((uint2*)(hrow + 16 + nh * 8 + q * 2)) = make_uint2(l0w, l1w);
            }
            const v8s bH = __builtin_bit_cast(v8s, *((const uint4*)(hrow + q * 4)));
            const v8s bL = __builtin_bit_cast(v8s, *((const uint4*)(hrow + 16 + q * 4)));

            #pragma unroll
            for (int nt = 0; nt < 4; ++nt) {
                const v8s a_h = __builtin_bit_cast(v8s, w1LDS[tOff + (nt * 2 + ks) * 64 + lane]);
                const v8s a_l = __builtin_bit_cast(v8s, w1LDS[tOff + 512 + (nt * 2 + ks) * 64 + lane]);
                v4f c = acc1[nt];
                c = __builtin_amdgcn_mfma_f32_16x16x32_bf16(a_l, bH, c, 0, 0, 0);
                c = __builtin_amdgcn_mfma_f32_16x16x32_bf16(a_h, bL, c, 0, 0, 0);
                c = __builtin_amdgcn_mfma_f32_16x16x32_bf16(a_h, bH, c, 0, 0, 0);
                acc1[nt] = c;
            }
        }

        // ---- L2 (64->3) in VALU: W2 direct from global (768 B, L1-hot) ----
        float o0 = 0.f, o1 = 0.f, o2 = 0.f;
        #pragma unroll
        for (int nt = 0; nt < 4; ++nt) {
            const int n0 = nt * 16 + q * 4;
            const float4 g0 = *((const float4*)(W2 + n0 * 3 + tOff));
            const float4 g1 = *((const float4*)(W2 + n0 * 3 + tOff + 4));
            const float4 g2 = *((const float4*)(W2 + n0 * 3 + tOff + 8));
            const float h0r = fmaxf(acc1[nt][0], 0.f), h1r = fmaxf(acc1[nt][1], 0.f);
            const float h2r = fmaxf(acc1[nt][2], 0.f), h3r = fmaxf(acc1[nt][3], 0.f);
            o0 = fmaf(h0r, g0.x, fmaf(h1r, g0.w, fmaf(h2r, g1.z, fmaf(h3r, g2.y, o0))));
            o1 = fmaf(h0r, g0.y, fmaf(h1r, g1.x, fmaf(h2r, g1.w, fmaf(h3r, g2.z, o1))));
            o2 = fmaf(h0r, g0.z, fmaf(h1r, g1.y, fmaf(h2r, g2.x, fmaf(h3r, g2.w, o2))));
        }
        o0 += __shfl_xor(o0, 16); o0 += __shfl_xor(o0, 32);
        o1 += __shfl_xor(o1, 16); o1 += __shfl_xor(o1, 32);
        o2 += __shfl_xor(o2, 16); o2 += __shfl_xor(o2, 32);

        if (lane < 16) {
            const int p = blockBase + wave * 64 + t * 16 + lane;
            out[p] = o0;
            out[NPTS + p] = o1;
            out[2 * NPTS + p] = o2;
        }
    }
}

extern "C" void kernel_launch(void* const* d_in, const int* in_sizes, int n_in,
                              void* d_out, int out_size, void* d_ws, size_t ws_size,
                              hipStream_t stream) {
    const float* xy     = (const float*)d_in[0];
    const float* tables = (const float*)d_in[1];
    const float* W0     = (const float*)d_in[2];
    const float* W1     = (const float*)d_in[3];
    const float* W2     = (const float*)d_in[4];
    float* out = (float*)d_out;
    uint4* ws  = (uint4*)d_ws;   // 1536 x 16B = 24 KB

    hipLaunchKernelGGL(prep_weights, dim3(3), dim3(256), 0, stream, W0, W1, ws);
    hipLaunchKernelGGL(ngp_mfma, dim3(NPTS / 256), dim3(256), 0, stream,
                       xy, tables, W2, ws, out);
}

// Round 10
// 167.993 us; speedup vs baseline: 1.0429x; 1.0155x over previous
//
#include <hip/hip_runtime.h>
#include <cstdint>
#include <cstddef>

#define S_DIM 1024
#define NPTS (S_DIM * S_DIM)
#define NLEV 16
#define TBL (1u << 19)
#define TMASK (TBL - 1u)
#define PRIME_Y 2654435761u

typedef float v4f __attribute__((ext_vector_type(4)));
typedef short v8s __attribute__((ext_vector_type(8)));
typedef float f2 __attribute__((ext_vector_type(2)));
typedef float f4 __attribute__((ext_vector_type(4)));

// all 16 level resolutions; levels 0-9 are DENSE ((res+1)^2 <= 2^19), 10-15 hashed
static constexpr int RES_ALL[NLEV] = {16, 24, 36, 54, 81, 121, 182, 273,
                                      410, 615, 922, 1383, 2075, 3113, 4670, 7006};
// dense-level corner staging (r8-verified): distinct corner-x count per level
// and prefix offsets (float4 units). Sum = 477 (7632 B).
static constexpr int DCNT[10] = {6, 8, 11, 16, 23, 33, 48, 71, 105, 156};
static constexpr int DOFF[10] = {0, 6, 14, 25, 41, 64, 97, 145, 216, 321};
#define DTOT 477

// ---- split-bf16: x = hi + lo, both truncated bf16.  v_perm_b32 packs each
// output word in ONE op -- bit-identical to shift/or, 6 ops total. ----
__device__ __forceinline__ void split2(float a, float b, uint32_t& hi, uint32_t& lo) {
    uint32_t ua = __float_as_uint(a), ub = __float_as_uint(b);
    float la = a - __uint_as_float(ua & 0xFFFF0000u);
    float lb = b - __uint_as_float(ub & 0xFFFF0000u);
    hi = __builtin_amdgcn_perm(ub, ua, 0x07060302u);
    lo = __builtin_amdgcn_perm(__float_as_uint(lb), __float_as_uint(la), 0x07060302u);
}

// ============================================================================
// Pre-pass (3 blocks): bf16 hi/lo A-fragments of W0^T and W1^T into d_ws.
// ws as uint4: [0,256) W0hi | [256,512) W0lo | [512,1024) W1hi | [1024,1536) W1lo
// ============================================================================
__global__ __launch_bounds__(256) void prep_weights(const float* __restrict__ W0,
                                                    const float* __restrict__ W1,
                                                    uint4* __restrict__ ws) {
    const int tid = threadIdx.x;          // 0..255
    const int b = blockIdx.x;             // 0..2

    if (b == 0) {   // W0^T: 4 n-tiles, 1 k-step. unit = tid.
        const int lane = tid & 63;
        const int m = lane & 15, q = lane >> 4;
        const int tile = tid >> 6;
        const int n = tile * 16 + m;
        uint32_t hi[4], lo[4];
        #pragma unroll
        for (int d = 0; d < 4; ++d) {
            const int k0 = q * 8 + 2 * d;
            split2(W0[k0 * 64 + n], W0[(k0 + 1) * 64 + n], hi[d], lo[d]);
        }
        ws[tid]       = make_uint4(hi[0], hi[1], hi[2], hi[3]);
        ws[256 + tid] = make_uint4(lo[0], lo[1], lo[2], lo[3]);
    } else {        // W1^T: 8 frags (nt*2+ks) x 64 lanes; unit in [0,512)
        const int unit = tid + (b - 1) * 256;
        const int l2 = unit & 63, frag = unit >> 6;
        const int nt = frag >> 1, ks = frag & 1;
        const int mm = l2 & 15, qq = l2 >> 4;
        const int n = nt * 16 + mm;
        uint32_t hi[4], lo[4];
        #pragma unroll
        for (int d = 0; d < 4; ++d) {
            const int k0 = ks * 32 + qq * 8 + 2 * d;
            split2(W1[k0 * 64 + n], W1[(k0 + 1) * 64 + n], hi[d], lo[d]);
        }
        ws[512 + unit]  = make_uint4(hi[0], hi[1], hi[2], hi[3]);
        ws[1024 + unit] = make_uint4(lo[0], lo[1], lo[2], lo[3]);
    }
}

// ---- hash-level gather/interp, two-stage so gathers can issue early --------
struct HashLvl {
    f2 f00, f01, f10, f11;
    float wx, wy;
};
static __device__ __forceinline__ HashLvl hash_load(float x, float y, int res,
                                                    const float* __restrict__ tb) {
    const float fr = (float)res;
    const float px = x * fr, py = y * fr;
    const float fx = floorf(px), fy = floorf(py);
    HashLvl h;
    h.wx = px - fx;
    h.wy = py - fy;
    const unsigned a = (unsigned)(int)fx, b = (unsigned)(int)fy;
    const unsigned hb0 = b * PRIME_Y;
    const unsigned hb1 = hb0 + PRIME_Y;          // == (b+1)*PRIME mod 2^32
    const int i00 = (int)((a ^ hb0) & TMASK);
    const int i01 = (int)((a ^ hb1) & TMASK);
    const int i10 = (int)(((a + 1u) ^ hb0) & TMASK);
    const int i11 = (int)(((a + 1u) ^ hb1) & TMASK);
    h.f00 = *(const f2*)(tb + 2 * (size_t)i00);
    h.f01 = *(const f2*)(tb + 2 * (size_t)i01);
    h.f10 = *(const f2*)(tb + 2 * (size_t)i10);
    h.f11 = *(const f2*)(tb + 2 * (size_t)i11);
    return h;
}
static __device__ __forceinline__ f2 hash_interp(const HashLvl& h) {
    const float omx = 1.f - h.wx, omy = 1.f - h.wy;
    const float w00 = omx * omy, w01 = omx * h.wy;
    const float w10 = h.wx * omy, w11 = h.wx * h.wy;
    return h.f00 * w00 + h.f01 * w01 + h.f10 * w10 + h.f11 * w11;
}

// ---- dense-level interp from the LDS corner stage (packed f32) -------------
static __device__ __forceinline__ f2 dense_interp(const f4* __restrict__ stage,
                                                  int l, f2 p, float p00x) {
    const float fr = (float)RES_ALL[l];
    const float px = p.x * fr, py = p.y * fr;
    const float fx = floorf(px), fy = floorf(py);
    const float wx = px - fx, wy = py - fy;
    const int xi = (int)fx - (int)floorf(p00x * fr);
    const f4 c0 = stage[DOFF[l] + xi];       // f00 | f01
    const f4 c1 = stage[DOFF[l] + xi + 1];   // f10 | f11
    const float omx = 1.f - wx, omy = 1.f - wy;
    const float w00 = omx * omy, w01 = omx * wy;
    const float w10 = wx * omy,  w11 = wx * wy;
    return c0.xy * w00 + c0.zw * w01 + c1.xy * w10 + c1.zw * w11;
}

// ============================================================================
// Main kernel.  r9 structure (3 blocks/CU, no spill, dense corner staging,
// perm split2, packed interp) + round-10 LATENCY work (r9 lesson: kernel is
// dependency-chain bound — occupancy/gather/VALU cuts all gave only ~4%):
//   - Phase 0/1 issue order: stage LOADS -> all 24 hash gathers -> stage
//     WRITES.  vmcnt retires oldest-first, so the stage ds_write waits only
//     on its own loads (vmcnt(24)) while hash gathers stay in flight through
//     the writes + barrier + dense groups (~800 cy of cover vs r9's ~400).
//   - Phase 2 t-loop UNROLL 2: two tiles' chains interleave; tile B's
//     eH/eL read + L0 fill tile A's bounce LDS round-trip + L1 stalls.
//     Live audit ~130 < 168 cap (VGPR was 68; 100 regs headroom).
// Spill tripwire: WRITE_SIZE > 30 MB means the reg budget failed.
// LDS map unchanged: enc 36864 + w1/stage 16384 = 53248 -> 3 blocks/CU.
// ============================================================================
__global__ __launch_bounds__(256, 3) void ngp_mfma(
    const float* __restrict__ xy,
    const float* __restrict__ tables,
    const float* __restrict__ W2,
    const uint4* __restrict__ ws,
    float* __restrict__ out)
{
    // enc rows: 256 points x (16 hi | 16 lo dwords) = 128B, padded to 144B.
    // Rows double as the per-tile h0 bounce space (r7/r8-verified).
    __shared__ alignas(16) uint32_t encLDS[256 * 36];        // 36864 B
    // Phase 1: dense corner stage (f4[477]).  Phase 2: W1^T fragments.
    __shared__ alignas(16) uint4 w1LDS[1024];                // 16384 B
    // total: 53248 B = 26 x 2048 exactly -> 3 blocks/CU

    const int tid = threadIdx.x;
    const int lane = tid & 63;
    const int wave = tid >> 6;
    const int m = lane & 15, q = lane >> 4;
    const int blockBase = blockIdx.x * 256;

    const float2 p00 = ((const float2*)xy)[blockBase];   // block's first point
    const f2 p = *((const f2*)(xy + 2 * (size_t)(blockBase + tid)));

    // ---------------- Phase 0a: stage LOADS (issue first = oldest) ----------
    // iter0 (u=tid) always valid; iter1 valid for tid < DTOT-256.
    f4 sv0, sv1;
    int su1valid = (tid + 256 < DTOT);
    {
        #pragma unroll
        for (int it = 0; it < 2; ++it) {
            const int u = tid + it * 256;
            if (it == 0 || su1valid) {
                int l = 0;
                #pragma unroll
                for (int k = 1; k < 10; ++k) l += (u >= DOFF[k]);
                const int r  = RES_ALL[l];
                const float fr = (float)r;
                const int X0 = (int)floorf(p00.x * fr);
                const int x  = min(X0 + (u - DOFF[l]), r);
                const int y0 = (int)floorf(p00.y * fr);
                const int st = r + 1;
                const float* tb = tables + (size_t)l * (size_t)(TBL * 2u);
                const float2 f0 = *(const float2*)(tb + 2 * (size_t)(x + y0 * st));
                const float2 f1 = *(const float2*)(tb + 2 * (size_t)(x + y0 * st + st));
                if (it == 0) sv0 = (f4){f0.x, f0.y, f1.x, f1.y};
                else         sv1 = (f4){f0.x, f0.y, f1.x, f1.y};
            }
        }
    }

    // ---------------- Phase 0b: issue ALL hash gathers (levels 10-15) ------
    // These stay in flight through the stage writes, the barrier, and the
    // dense groups below — consumed last.
    HashLvl hl[6];
    #pragma unroll
    for (int i = 0; i < 6; ++i)
        hl[i] = hash_load(p.x, p.y, RES_ALL[10 + i],
                          tables + (size_t)(10 + i) * (size_t)(TBL * 2u));

    // ---------------- Phase 0c: stage WRITES (wait only on own loads) ------
    {
        f4* stage = (f4*)w1LDS;
        stage[tid] = sv0;
        if (su1valid) stage[tid + 256] = sv1;
    }
    __syncthreads();   // stage visible to all waves

    // ---------------- Phase 1: encode own point ----------------
    {
        const f4* stage = (const f4*)w1LDS;
        uint32_t* row = encLDS + tid * 36;

        // dense groups 0,1 (levels 0-7) from LDS stage, under gather latency
        #pragma unroll
        for (int g = 0; g < 2; ++g) {
            uint32_t hi[4], lo[4];
            #pragma unroll
            for (int i = 0; i < 4; ++i) {
                const f2 e = dense_interp(stage, g * 4 + i, p, p00.x);
                split2(e.x, e.y, hi[i], lo[i]);
            }
            *((uint4*)(row + 4 * g))      = make_uint4(hi[0], hi[1], hi[2], hi[3]);
            *((uint4*)(row + 16 + 4 * g)) = make_uint4(lo[0], lo[1], lo[2], lo[3]);
        }
        // group 2 = levels 8,9 dense + 10,11 hashed (consume hl[0..1])
        {
            uint32_t hi[4], lo[4];
            #pragma unroll
            for (int i = 0; i < 2; ++i) {
                const f2 e = dense_interp(stage, 8 + i, p, p00.x);
                split2(e.x, e.y, hi[i], lo[i]);
            }
            #pragma unroll
            for (int i = 0; i < 2; ++i) {
                const f2 e = hash_interp(hl[i]);
                split2(e.x, e.y, hi[2 + i], lo[2 + i]);
            }
            *((uint4*)(row + 8))      = make_uint4(hi[0], hi[1], hi[2], hi[3]);
            *((uint4*)(row + 16 + 8)) = make_uint4(lo[0], lo[1], lo[2], lo[3]);
        }
        // group 3 = levels 12-15 hashed (consume hl[2..5])
        {
            uint32_t hi[4], lo[4];
            #pragma unroll
            for (int i = 0; i < 4; ++i) {
                const f2 e = hash_interp(hl[2 + i]);
                split2(e.x, e.y, hi[i], lo[i]);
            }
            *((uint4*)(row + 12))      = make_uint4(hi[0], hi[1], hi[2], hi[3]);
            *((uint4*)(row + 16 + 12)) = make_uint4(lo[0], lo[1], lo[2], lo[3]);
        }
    }

    __syncthreads();   // all waves done reading stage -> safe to overwrite

    // ---------------- stage W1 frags global->LDS (overwrites stage) --------
    #pragma unroll
    for (int i = 0; i < 4; ++i) w1LDS[tid + 256 * i] = ws[512 + tid + 256 * i];

    __syncthreads();   // w1LDS visible

    // keep encode and phase-2 live ranges disjoint: no motion across here
    __builtin_amdgcn_sched_barrier(0);

    // ---------------- W0 fragments: registers, reused by all 4 tiles -------
    v8s w0h[4], w0l[4];
    #pragma unroll
    for (int t = 0; t < 4; ++t) {
        w0h[t] = __builtin_bit_cast(v8s, ws[t * 64 + lane]);
        w0l[t] = __builtin_bit_cast(v8s, ws[256 + t * 64 + lane]);
    }

    // ---------------- Phase 2: 4 M-tiles, UNROLLED x2 for cross-tile ILP ---
    #pragma unroll 2
    for (int t = 0; t < 4; ++t) {
        // launder a zero through opaque asm so LICM cannot hoist the
        // per-tile w1LDS reads / W2 global reads out of this loop.
        int tOff = 0;
        asm volatile("" : "+v"(tOff));

        // this tile's enc row for lane's m — also the h0 bounce row.
        uint32_t* hrow = encLDS + (wave * 64 + t * 16 + m) * 36;

        // B-frag of enc: point p = wave*64 + t*16 + m
        const v8s eH = __builtin_bit_cast(v8s, *((const uint4*)(hrow + q * 4)));
        const v8s eL = __builtin_bit_cast(v8s, *((const uint4*)(hrow + 16 + q * 4)));

        // ---- L0: D0[n][p] = W0^T x enc^T, 3-term split ----
        v4f acc0[4];
        #pragma unroll
        for (int nt = 0; nt < 4; ++nt) {
            v4f c = {0.f, 0.f, 0.f, 0.f};
            c = __builtin_amdgcn_mfma_f32_16x16x32_bf16(w0l[nt], eH, c, 0, 0, 0);
            c = __builtin_amdgcn_mfma_f32_16x16x32_bf16(w0h[nt], eL, c, 0, 0, 0);
            c = __builtin_amdgcn_mfma_f32_16x16x32_bf16(w0h[nt], eH, c, 0, 0, 0);
            acc0[nt] = c;
        }

        v4f acc1[4];
        #pragma unroll
        for (int nt = 0; nt < 4; ++nt) acc1[nt] = (v4f){0.f, 0.f, 0.f, 0.f};

        // ---- L1 in two ks-halves, bouncing through this tile's enc rows ----
        #pragma unroll
        for (int ks = 0; ks < 2; ++ks) {
            #pragma unroll
            for (int nh = 0; nh < 2; ++nh) {
                const int nt = ks * 2 + nh;
                const float r0 = fmaxf(acc0[nt][0], 0.f), r1 = fmaxf(acc0[nt][1], 0.f);
                const float r2 = fmaxf(acc0[nt][2], 0.f), r3 = fmaxf(acc0[nt][3], 0.f);
                uint32_t h0w, l0w, h1w, l1w;
                split2(r0, r1, h0w, l0w);
                split2(r2, r3, h1w, l1w);
                *((uint2*)(hrow + nh * 8 + q * 2))      = make_uint2(h0w, h1w);
                *((uint2*)(hrow + 16 + nh * 8 + q * 2)) = make_uint2(l0w, l1w);
            }
            const v8s bH = __builtin_bit_cast(v8s, *((const uint4*)(hrow + q * 4)));
            const v8s bL = __builtin_bit_cast(v8s, *((const uint4*)(hrow + 16 + q * 4)));

            #pragma unroll
            for (int nt = 0; nt < 4; ++nt) {
                const v8s a_h = __builtin_bit_cast(v8s, w1LDS[tOff + (nt * 2 + ks) * 64 + lane]);
                const v8s a_l = __builtin_bit_cast(v8s, w1LDS[tOff + 512 + (nt * 2 + ks) * 64 + lane]);
                v4f c = acc1[nt];
                c = __builtin_amdgcn_mfma_f32_16x16x32_bf16(a_l, bH, c, 0, 0, 0);
                c = __builtin_amdgcn_mfma_f32_16x16x32_bf16(a_h, bL, c, 0, 0, 0);
                c = __builtin_amdgcn_mfma_f32_16x16x32_bf16(a_h, bH, c, 0, 0, 0);
                acc1[nt] = c;
            }
        }

        // ---- L2 (64->3) in VALU: W2 direct from global (768 B, L1-hot) ----
        float o0 = 0.f, o1 = 0.f, o2 = 0.f;
        #pragma unroll
        for (int nt = 0; nt < 4; ++nt) {
            const int n0 = nt * 16 + q * 4;
            const float4 g0 = *((const float4*)(W2 + n0 * 3 + tOff));
            const float4 g1 = *((const float4*)(W2 + n0 * 3 + tOff + 4));
            const float4 g2 = *((const float4*)(W2 + n0 * 3 + tOff + 8));
            const float h0r = fmaxf(acc1[nt][0], 0.f), h1r = fmaxf(acc1[nt][1], 0.f);
            const float h2r = fmaxf(acc1[nt][2], 0.f), h3r = fmaxf(acc1[nt][3], 0.f);
            o0 = fmaf(h0r, g0.x, fmaf(h1r, g0.w, fmaf(h2r, g1.z, fmaf(h3r, g2.y, o0))));
            o1 = fmaf(h0r, g0.y, fmaf(h1r, g1.x, fmaf(h2r, g1.w, fmaf(h3r, g2.z, o1))));
            o2 = fmaf(h0r, g0.z, fmaf(h1r, g1.y, fmaf(h2r, g2.x, fmaf(h3r, g2.w, o2))));
        }
        o0 += __shfl_xor(o0, 16); o0 += __shfl_xor(o0, 32);
        o1 += __shfl_xor(o1, 16); o1 += __shfl_xor(o1, 32);
        o2 += __shfl_xor(o2, 16); o2 += __shfl_xor(o2, 32);

        if (lane < 16) {
            const int p2 = blockBase + wave * 64 + t * 16 + lane;
            out[p2] = o0;
            out[NPTS + p2] = o1;
            out[2 * NPTS + p2] = o2;
        }
    }
}

extern "C" void kernel_launch(void* const* d_in, const int* in_sizes, int n_in,
                              void* d_out, int out_size, void* d_ws, size_t ws_size,
                              hipStream_t stream) {
    const float* xy     = (const float*)d_in[0];
    const float* tables = (const float*)d_in[1];
    const float* W0     = (const float*)d_in[2];
    const float* W1     = (const float*)d_in[3];
    const float* W2     = (const float*)d_in[4];
    float* out = (float*)d_out;
    uint4* ws  = (uint4*)d_ws;   // 1536 x 16B = 24 KB

    hipLaunchKernelGGL(prep_weights, dim3(3), dim3(256), 0, stream, W0, W1, ws);
    hipLaunchKernelGGL(ngp_mfma, dim3(NPTS / 256), dim3(256), 0, stream,
                       xy, tables, W2, ws, out);
}

// Round 12
// 167.170 us; speedup vs baseline: 1.0480x; 1.0049x over previous
//
#include <hip/hip_runtime.h>
#include <cstdint>
#include <cstddef>

#define S_DIM 1024
#define NPTS (S_DIM * S_DIM)
#define NLEV 16
#define TBL (1u << 19)
#define TMASK (TBL - 1u)
#define PRIME_Y 2654435761u

typedef float v4f __attribute__((ext_vector_type(4)));
typedef short v8s __attribute__((ext_vector_type(8)));
typedef float f2 __attribute__((ext_vector_type(2)));
typedef float f4 __attribute__((ext_vector_type(4)));

// may_alias access types for the encLDS bounce region: the bounce WRITES
// (2-dword) and the b-frag/e-frag READS (4-dword) hit the same uint32_t LDS
// words with no barrier between them.  Plain uint2*/uint4* casts let TBAA
// declare them independent -> the scheduler may reorder the reads past the
// writes (round-11 failure mode).  may_alias pins the dependency.
typedef uint2 uint2_a __attribute__((may_alias));
typedef uint4 uint4_a __attribute__((may_alias));

// all 16 level resolutions; levels 0-9 are DENSE ((res+1)^2 <= 2^19), 10-15 hashed
static constexpr int RES_ALL[NLEV] = {16, 24, 36, 54, 81, 121, 182, 273,
                                      410, 615, 922, 1383, 2075, 3113, 4670, 7006};
// dense-level corner staging (r8-verified): distinct corner-x count per level
// and prefix offsets (float4 units). Sum = 477 (7632 B).
static constexpr int DCNT[10] = {6, 8, 11, 16, 23, 33, 48, 71, 105, 156};
static constexpr int DOFF[10] = {0, 6, 14, 25, 41, 64, 97, 145, 216, 321};
#define DTOT 477

// ---- split-bf16: x = hi + lo, both truncated bf16.  v_perm_b32 packs each
// output word in ONE op -- bit-identical to shift/or, 6 ops total. ----
__device__ __forceinline__ void split2(float a, float b, uint32_t& hi, uint32_t& lo) {
    uint32_t ua = __float_as_uint(a), ub = __float_as_uint(b);
    float la = a - __uint_as_float(ua & 0xFFFF0000u);
    float lb = b - __uint_as_float(ub & 0xFFFF0000u);
    hi = __builtin_amdgcn_perm(ub, ua, 0x07060302u);
    lo = __builtin_amdgcn_perm(__float_as_uint(lb), __float_as_uint(la), 0x07060302u);
}

// ============================================================================
// Pre-pass (3 blocks): bf16 hi/lo A-fragments of W0^T and W1^T into d_ws.
// ws as uint4: [0,256) W0hi | [256,512) W0lo | [512,1024) W1hi | [1024,1536) W1lo
// ============================================================================
__global__ __launch_bounds__(256) void prep_weights(const float* __restrict__ W0,
                                                    const float* __restrict__ W1,
                                                    uint4* __restrict__ ws) {
    const int tid = threadIdx.x;          // 0..255
    const int b = blockIdx.x;             // 0..2

    if (b == 0) {   // W0^T: 4 n-tiles, 1 k-step. unit = tid.
        const int lane = tid & 63;
        const int m = lane & 15, q = lane >> 4;
        const int tile = tid >> 6;
        const int n = tile * 16 + m;
        uint32_t hi[4], lo[4];
        #pragma unroll
        for (int d = 0; d < 4; ++d) {
            const int k0 = q * 8 + 2 * d;
            split2(W0[k0 * 64 + n], W0[(k0 + 1) * 64 + n], hi[d], lo[d]);
        }
        ws[tid]       = make_uint4(hi[0], hi[1], hi[2], hi[3]);
        ws[256 + tid] = make_uint4(lo[0], lo[1], lo[2], lo[3]);
    } else {        // W1^T: 8 frags (nt*2+ks) x 64 lanes; unit in [0,512)
        const int unit = tid + (b - 1) * 256;
        const int l2 = unit & 63, frag = unit >> 6;
        const int nt = frag >> 1, ks = frag & 1;
        const int mm = l2 & 15, qq = l2 >> 4;
        const int n = nt * 16 + mm;
        uint32_t hi[4], lo[4];
        #pragma unroll
        for (int d = 0; d < 4; ++d) {
            const int k0 = ks * 32 + qq * 8 + 2 * d;
            split2(W1[k0 * 64 + n], W1[(k0 + 1) * 64 + n], hi[d], lo[d]);
        }
        ws[512 + unit]  = make_uint4(hi[0], hi[1], hi[2], hi[3]);
        ws[1024 + unit] = make_uint4(lo[0], lo[1], lo[2], lo[3]);
    }
}

// ---- hash-level gather/interp, two-stage so gathers can issue early --------
struct HashLvl {
    f2 f00, f01, f10, f11;
    float wx, wy;
};
static __device__ __forceinline__ HashLvl hash_load(float x, float y, int res,
                                                    const float* __restrict__ tb) {
    const float fr = (float)res;
    const float px = x * fr, py = y * fr;
    const float fx = floorf(px), fy = floorf(py);
    HashLvl h;
    h.wx = px - fx;
    h.wy = py - fy;
    const unsigned a = (unsigned)(int)fx, b = (unsigned)(int)fy;
    const unsigned hb0 = b * PRIME_Y;
    const unsigned hb1 = hb0 + PRIME_Y;          // == (b+1)*PRIME mod 2^32
    const int i00 = (int)((a ^ hb0) & TMASK);
    const int i01 = (int)((a ^ hb1) & TMASK);
    const int i10 = (int)(((a + 1u) ^ hb0) & TMASK);
    const int i11 = (int)(((a + 1u) ^ hb1) & TMASK);
    h.f00 = *(const f2*)(tb + 2 * (size_t)i00);
    h.f01 = *(const f2*)(tb + 2 * (size_t)i01);
    h.f10 = *(const f2*)(tb + 2 * (size_t)i10);
    h.f11 = *(const f2*)(tb + 2 * (size_t)i11);
    return h;
}
static __device__ __forceinline__ f2 hash_interp(const HashLvl& h) {
    const float omx = 1.f - h.wx, omy = 1.f - h.wy;
    const float w00 = omx * omy, w01 = omx * h.wy;
    const float w10 = h.wx * omy, w11 = h.wx * h.wy;
    return h.f00 * w00 + h.f01 * w01 + h.f10 * w10 + h.f11 * w11;
}

// ---- dense-level interp from the LDS corner stage (packed f32) -------------
static __device__ __forceinline__ f2 dense_interp(const f4* __restrict__ stage,
                                                  int l, f2 p, float p00x) {
    const float fr = (float)RES_ALL[l];
    const float px = p.x * fr, py = p.y * fr;
    const float fx = floorf(px), fy = floorf(py);
    const float wx = px - fx, wy = py - fy;
    const int xi = (int)fx - (int)floorf(p00x * fr);
    const f4 c0 = stage[DOFF[l] + xi];       // f00 | f01
    const f4 c1 = stage[DOFF[l] + xi + 1];   // f10 | f11
    const float omx = 1.f - wx, omy = 1.f - wy;
    const float w00 = omx * omy, w01 = omx * wy;
    const float w10 = wx * omy,  w11 = wx * wy;
    return c0.xy * w00 + c0.zw * w01 + c1.xy * w10 + c1.zw * w11;
}

// ============================================================================
// Main kernel.  r10 structure (last verified, 83.5 us main) + round-12 fixes:
//   - TBAA FIX: bounce writes (uint2) and b-frag/e-frag reads (uint4) on the
//     same LDS words now use may_alias types.  r11's pair-pipeline failed
//     because plain-cast TBAA let the scheduler reorder the uint4 reads past
//     the uint2 writes once the scheduling window grew.  Latent since r5.
//   - E-FRAG PREFETCH: tile t+1's eH/eL are read BEFORE tile t's bounce
//     writes.  Addresses provably disjoint (constant +576-dword offset), so
//     this is reorder-safe, and removes an LDS-read stall per tile head.
// Phase 0/1 (stage loads -> hash gathers in flight -> stage writes -> dense
// interp), LDS map (enc 36864 + w1/stage 16384 = 53248 -> 3 blocks/CU),
// prep_weights: unchanged from r10.
// Spill tripwire: WRITE_SIZE > 30 MB means the reg budget failed.
// ============================================================================
__global__ __launch_bounds__(256, 3) void ngp_mfma(
    const float* __restrict__ xy,
    const float* __restrict__ tables,
    const float* __restrict__ W2,
    const uint4* __restrict__ ws,
    float* __restrict__ out)
{
    __shared__ alignas(16) uint32_t encLDS[256 * 36];        // 36864 B
    __shared__ alignas(16) uint4 w1LDS[1024];                // 16384 B

    const int tid = threadIdx.x;
    const int lane = tid & 63;
    const int wave = tid >> 6;
    const int m = lane & 15, q = lane >> 4;
    const int blockBase = blockIdx.x * 256;

    const float2 p00 = ((const float2*)xy)[blockBase];   // block's first point
    const f2 p = *((const f2*)(xy + 2 * (size_t)(blockBase + tid)));

    // ---------------- Phase 0a: stage LOADS (issue first = oldest) ----------
    f4 sv0, sv1;
    int su1valid = (tid + 256 < DTOT);
    {
        #pragma unroll
        for (int it = 0; it < 2; ++it) {
            const int u = tid + it * 256;
            if (it == 0 || su1valid) {
                int l = 0;
                #pragma unroll
                for (int k = 1; k < 10; ++k) l += (u >= DOFF[k]);
                const int r  = RES_ALL[l];
                const float fr = (float)r;
                const int X0 = (int)floorf(p00.x * fr);
                const int x  = min(X0 + (u - DOFF[l]), r);
                const int y0 = (int)floorf(p00.y * fr);
                const int st = r + 1;
                const float* tb = tables + (size_t)l * (size_t)(TBL * 2u);
                const float2 f0 = *(const float2*)(tb + 2 * (size_t)(x + y0 * st));
                const float2 f1 = *(const float2*)(tb + 2 * (size_t)(x + y0 * st + st));
                if (it == 0) sv0 = (f4){f0.x, f0.y, f1.x, f1.y};
                else         sv1 = (f4){f0.x, f0.y, f1.x, f1.y};
            }
        }
    }

    // ---------------- Phase 0b: issue ALL hash gathers (levels 10-15) ------
    HashLvl hl[6];
    #pragma unroll
    for (int i = 0; i < 6; ++i)
        hl[i] = hash_load(p.x, p.y, RES_ALL[10 + i],
                          tables + (size_t)(10 + i) * (size_t)(TBL * 2u));

    // ---------------- Phase 0c: stage WRITES (wait only on own loads) ------
    {
        f4* stage = (f4*)w1LDS;
        stage[tid] = sv0;
        if (su1valid) stage[tid + 256] = sv1;
    }
    __syncthreads();   // stage visible to all waves

    // ---------------- Phase 1: encode own point ----------------
    {
        const f4* stage = (const f4*)w1LDS;
        uint32_t* row = encLDS + tid * 36;

        #pragma unroll
        for (int g = 0; g < 2; ++g) {
            uint32_t hi[4], lo[4];
            #pragma unroll
            for (int i = 0; i < 4; ++i) {
                const f2 e = dense_interp(stage, g * 4 + i, p, p00.x);
                split2(e.x, e.y, hi[i], lo[i]);
            }
            *((uint4_a*)(row + 4 * g))      = make_uint4(hi[0], hi[1], hi[2], hi[3]);
            *((uint4_a*)(row + 16 + 4 * g)) = make_uint4(lo[0], lo[1], lo[2], lo[3]);
        }
        {
            uint32_t hi[4], lo[4];
            #pragma unroll
            for (int i = 0; i < 2; ++i) {
                const f2 e = dense_interp(stage, 8 + i, p, p00.x);
                split2(e.x, e.y, hi[i], lo[i]);
            }
            #pragma unroll
            for (int i = 0; i < 2; ++i) {
                const f2 e = hash_interp(hl[i]);
                split2(e.x, e.y, hi[2 + i], lo[2 + i]);
            }
            *((uint4_a*)(row + 8))      = make_uint4(hi[0], hi[1], hi[2], hi[3]);
            *((uint4_a*)(row + 16 + 8)) = make_uint4(lo[0], lo[1], lo[2], lo[3]);
        }
        {
            uint32_t hi[4], lo[4];
            #pragma unroll
            for (int i = 0; i < 4; ++i) {
                const f2 e = hash_interp(hl[2 + i]);
                split2(e.x, e.y, hi[i], lo[i]);
            }
            *((uint4_a*)(row + 12))      = make_uint4(hi[0], hi[1], hi[2], hi[3]);
            *((uint4_a*)(row + 16 + 12)) = make_uint4(lo[0], lo[1], lo[2], lo[3]);
        }
    }

    __syncthreads();   // all waves done reading stage -> safe to overwrite

    // ---------------- stage W1 frags global->LDS (overwrites stage) --------
    #pragma unroll
    for (int i = 0; i < 4; ++i) w1LDS[tid + 256 * i] = ws[512 + tid + 256 * i];

    __syncthreads();   // w1LDS visible

    __builtin_amdgcn_sched_barrier(0);

    // ---------------- W0 fragments: registers, reused by all 4 tiles -------
    v8s w0h[4], w0l[4];
    #pragma unroll
    for (int t = 0; t < 4; ++t) {
        w0h[t] = __builtin_bit_cast(v8s, ws[t * 64 + lane]);
        w0l[t] = __builtin_bit_cast(v8s, ws[256 + t * 64 + lane]);
    }

    // ---- e-frags of tile 0, preloaded ----
    v8s eHc, eLc;
    {
        const uint32_t* r0 = encLDS + (wave * 64 + m) * 36;
        eHc = __builtin_bit_cast(v8s, *((const uint4_a*)(r0 + q * 4)));
        eLc = __builtin_bit_cast(v8s, *((const uint4_a*)(r0 + 16 + q * 4)));
    }

    // ---------------- Phase 2: 4 M-tiles, unroll 2, e-frag prefetch --------
    #pragma unroll 2
    for (int t = 0; t < 4; ++t) {
        // launder a zero through opaque asm so LICM cannot hoist the
        // per-tile w1LDS reads / W2 global reads out of this loop.
        int tOff = 0;
        asm volatile("" : "+v"(tOff));

        // this tile's enc row for lane's m — also the h0 bounce row.
        uint32_t* hrow = encLDS + (wave * 64 + t * 16 + m) * 36;

        // ---- PREFETCH next tile's e-frags (rows +16: disjoint from this
        // tile's bounce writes — value-safe under any reordering) ----
        v8s eHn = eHc, eLn = eLc;
        if (t < 3) {
            const uint32_t* rn = hrow + 16 * 36;
            eHn = __builtin_bit_cast(v8s, *((const uint4_a*)(rn + q * 4)));
            eLn = __builtin_bit_cast(v8s, *((const uint4_a*)(rn + 16 + q * 4)));
        }

        // ---- L0: D0[n][p] = W0^T x enc^T, 3-term split ----
        v4f acc0[4];
        #pragma unroll
        for (int nt = 0; nt < 4; ++nt) {
            v4f c = {0.f, 0.f, 0.f, 0.f};
            c = __builtin_amdgcn_mfma_f32_16x16x32_bf16(w0l[nt], eHc, c, 0, 0, 0);
            c = __builtin_amdgcn_mfma_f32_16x16x32_bf16(w0h[nt], eLc, c, 0, 0, 0);
            c = __builtin_amdgcn_mfma_f32_16x16x32_bf16(w0h[nt], eHc, c, 0, 0, 0);
            acc0[nt] = c;
        }

        v4f acc1[4];
        #pragma unroll
        for (int nt = 0; nt < 4; ++nt) acc1[nt] = (v4f){0.f, 0.f, 0.f, 0.f};

        // ---- L1 in two ks-halves, bouncing through this tile's enc rows ----
        #pragma unroll
        for (int ks = 0; ks < 2; ++ks) {
            #pragma unroll
            for (int nh = 0; nh < 2; ++nh) {
                const int nt = ks * 2 + nh;
                const float r0 = fmaxf(acc0[nt][0], 0.f), r1 = fmaxf(acc0[nt][1], 0.f);
                const float r2 = fmaxf(acc0[nt][2], 0.f), r3 = fmaxf(acc0[nt][3], 0.f);
                uint32_t h0w, l0w, h1w, l1w;
                split2(r0, r1, h0w, l0w);
                split2(r2, r3, h1w, l1w);
                *((uint2_a*)(hrow + nh * 8 + q * 2))      = make_uint2(h0w, h1w);
                *((uint2_a*)(hrow + 16 + nh * 8 + q * 2)) = make_uint2(l0w, l1w);
            }
            const v8s bH = __builtin_bit_cast(v8s, *((const uint4_a*)(hrow + q * 4)));
            const v8s bL = __builtin_bit_cast(v8s, *((const uint4_a*)(hrow + 16 + q * 4)));

            #pragma unroll
            for (int nt = 0; nt < 4; ++nt) {
                const v8s a_h = __builtin_bit_cast(v8s, w1LDS[tOff + (nt * 2 + ks) * 64 + lane]);
                const v8s a_l = __builtin_bit_cast(v8s, w1LDS[tOff + 512 + (nt * 2 + ks) * 64 + lane]);
                v4f c = acc1[nt];
                c = __builtin_amdgcn_mfma_f32_16x16x32_bf16(a_l, bH, c, 0, 0, 0);
                c = __builtin_amdgcn_mfma_f32_16x16x32_bf16(a_h, bL, c, 0, 0, 0);
                c = __builtin_amdgcn_mfma_f32_16x16x32_bf16(a_h, bH, c, 0, 0, 0);
                acc1[nt] = c;
            }
        }

        // ---- L2 (64->3) in VALU: W2 direct from global (768 B, L1-hot) ----
        float o0 = 0.f, o1 = 0.f, o2 = 0.f;
        #pragma unroll
        for (int nt = 0; nt < 4; ++nt) {
            const int n0 = nt * 16 + q * 4;
            const float4 g0 = *((const float4*)(W2 + n0 * 3 + tOff));
            const float4 g1 = *((const float4*)(W2 + n0 * 3 + tOff + 4));
            const float4 g2 = *((const float4*)(W2 + n0 * 3 + tOff + 8));
            const float h0r = fmaxf(acc1[nt][0], 0.f), h1r = fmaxf(acc1[nt][1], 0.f);
            const float h2r = fmaxf(acc1[nt][2], 0.f), h3r = fmaxf(acc1[nt][3], 0.f);
            o0 = fmaf(h0r, g0.x, fmaf(h1r, g0.w, fmaf(h2r, g1.z, fmaf(h3r, g2.y, o0))));
            o1 = fmaf(h0r, g0.y, fmaf(h1r, g1.x, fmaf(h2r, g1.w, fmaf(h3r, g2.z, o1))));
            o2 = fmaf(h0r, g0.z, fmaf(h1r, g1.y, fmaf(h2r, g2.x, fmaf(h3r, g2.w, o2))));
        }
        o0 += __shfl_xor(o0, 16); o0 += __shfl_xor(o0, 32);
        o1 += __shfl_xor(o1, 16); o1 += __shfl_xor(o1, 32);
        o2 += __shfl_xor(o2, 16); o2 += __shfl_xor(o2, 32);

        if (lane < 16) {
            const int p2 = blockBase + wave * 64 + t * 16 + lane;
            out[p2] = o0;
            out[NPTS + p2] = o1;
            out[2 * NPTS + p2] = o2;
        }

        // rotate prefetched e-frags into place for the next tile
        eHc = eHn;
        eLc = eLn;
    }
}

extern "C" void kernel_launch(void* const* d_in, const int* in_sizes, int n_in,
                              void* d_out, int out_size, void* d_ws, size_t ws_size,
                              hipStream_t stream) {
    const float* xy     = (const float*)d_in[0];
    const float* tables = (const float*)d_in[1];
    const float* W0     = (const float*)d_in[2];
    const float* W1     = (const float*)d_in[3];
    const float* W2     = (const float*)d_in[4];
    float* out = (float*)d_out;
    uint4* ws  = (uint4*)d_ws;   // 1536 x 16B = 24 KB

    hipLaunchKernelGGL(prep_weights, dim3(3), dim3(256), 0, stream, W0, W1, ws);
    hipLaunchKernelGGL(ngp_mfma, dim3(NPTS / 256), dim3(256), 0, stream,
                       xy, tables, W2, ws, out);
}